// Round 1
// baseline (379.202 us; speedup 1.0000x reference)
//
#include <hip/hip_runtime.h>
#include <math.h>

#define B_ 64
#define P_ 8732
#define M_ 16
#define C_ 81
#define THRESH 0.5f
#define EPS_ 1e-7f

// ce_loc grid: 3 blocks/CU * 256 CUs
#define CE_GRID 768
#define NBLK_CE CE_GRID
#define ROWS_PER_CHUNK 64
#define NCHUNKS ((B_ * P_) / ROWS_PER_CHUNK)        // 558848/64 = 8732 exact
#define CHUNK_F4 (ROWS_PER_CHUNK * C_ / 4)          // 1296 float4 = 5*256 + 16

// ---------------------------------------------------------------------------
// Kernel 1: per-batch prior assignment. 1024 threads/block, one block/batch.
// Faithful to reference incl. j_idx filtered-index bug + last-write-wins.
// (unchanged from verified version)
// ---------------------------------------------------------------------------
__global__ __launch_bounds__(1024) void assign_kernel(
    const float* __restrict__ boxes,    // [B,M,4] corner
    const int*   __restrict__ labels,   // [B,M]
    const float* __restrict__ priors,   // [P,4] cxcy
    int*         __restrict__ true_classes, // [B,P]
    int*         __restrict__ n_pos)    // [B]
{
    const int b = blockIdx.x;
    const int tid = threadIdx.x;
    const int lane = tid & 63;
    const int wv = tid >> 6;            // 16 waves

    __shared__ float s_ovl[P_];
    __shared__ unsigned char s_obj[P_];
    __shared__ float s_bx[M_][4];
    __shared__ float s_barea[M_];
    __shared__ int   s_lab[M_];
    __shared__ float s_wv[M_][16];
    __shared__ int   s_wp[M_][16];
    __shared__ float s_ovl_obj[M_];
    __shared__ int   s_prior_obj[M_];
    __shared__ int   s_cnt[16];

    if (tid < M_*4) ((float*)s_bx)[tid] = boxes[b*M_*4 + tid];
    if (tid < M_)   s_lab[tid] = labels[b*M_ + tid];
    __syncthreads();
    if (tid < M_)
        s_barea[tid] = (s_bx[tid][2]-s_bx[tid][0])*(s_bx[tid][3]-s_bx[tid][1]);
    __syncthreads();

    float bestv[M_]; int bestp[M_];
    #pragma unroll
    for (int m = 0; m < M_; ++m) { bestv[m] = -1.0f; bestp[m] = 0x7fffffff; }

    for (int p = tid; p < P_; p += 1024) {
        float4 pc = ((const float4*)priors)[p];
        float px1 = pc.x - pc.z*0.5f, py1 = pc.y - pc.w*0.5f;
        float px2 = pc.x + pc.z*0.5f, py2 = pc.y + pc.w*0.5f;
        float parea = (px2-px1)*(py2-py1);
        float bv = -1.0f; int bm = 0;
        #pragma unroll
        for (int m = 0; m < M_; ++m) {
            float ix1 = fmaxf(s_bx[m][0], px1);
            float iy1 = fmaxf(s_bx[m][1], py1);
            float ix2 = fminf(s_bx[m][2], px2);
            float iy2 = fminf(s_bx[m][3], py2);
            float iw = fmaxf(ix2-ix1, 0.0f);
            float ih = fmaxf(iy2-iy1, 0.0f);
            float inter = iw*ih;
            float iou = inter / (s_barea[m] + parea - inter); // jaccard: no eps
            if (iou > bv) { bv = iou; bm = m; }               // first-max (m asc)
            if (iou > bestv[m]) { bestv[m] = iou; bestp[m] = p; } // first p wins
        }
        s_ovl[p] = bv;
        s_obj[p] = (unsigned char)bm;
    }

    #pragma unroll
    for (int m = 0; m < M_; ++m) {
        float v = bestv[m]; int p = bestp[m];
        #pragma unroll
        for (int o = 32; o; o >>= 1) {
            float v2 = __shfl_xor(v, o);
            int   p2 = __shfl_xor(p, o);
            if (v2 > v || (v2 == v && p2 < p)) { v = v2; p = p2; }
        }
        if (lane == 0) { s_wv[m][wv] = v; s_wp[m][wv] = p; }
    }
    __syncthreads();

    if (tid < M_) {
        float v = s_wv[tid][0]; int p = s_wp[tid][0];
        #pragma unroll
        for (int w = 1; w < 16; ++w) {
            float v2 = s_wv[tid][w]; int p2 = s_wp[tid][w];
            if (v2 > v || (v2 == v && p2 < p)) { v = v2; p = p2; }
        }
        s_ovl_obj[tid] = v; s_prior_obj[tid] = p;
    }
    __syncthreads();

    if (tid == 0) {
        int cnt = 0;
        for (int m = 0; m < M_; ++m) {
            if (s_ovl_obj[m] > 0.0f) {
                int p = s_prior_obj[m];
                s_ovl[p] = 1.0f;
                s_obj[p] = (unsigned char)cnt;  // filtered index (faithful)
                cnt++;
            }
        }
    }
    __syncthreads();

    int cpos = 0;
    for (int p = tid; p < P_; p += 1024) {
        int tc = 0;
        if (!(s_ovl[p] < THRESH)) tc = s_lab[s_obj[p]];
        true_classes[(size_t)b*P_ + p] = tc;
        cpos += (tc > 0);
    }
    #pragma unroll
    for (int o = 32; o; o >>= 1) cpos += __shfl_xor(cpos, o);
    if (lane == 0) s_cnt[wv] = cpos;
    __syncthreads();
    if (tid == 0) {
        int t = 0;
        #pragma unroll
        for (int w = 0; w < 16; ++w) t += s_cnt[w];
        n_pos[b] = t;
    }
}

// ---------------------------------------------------------------------------
// Kernel 2 (rewritten): CE over C=81 + positive-gated DIoU self-loss.
// Double-buffered LDS streaming: a 64-row chunk = exactly 1296 aligned
// float4s -> fully coalesced 16B/lane staging (T14 issue-early/write-late).
// Compute: 4 lanes per row (cols 21/20/20/20) reading LDS at word-stride 81
// (odd stride -> bank permutation, ~2 lanes/bank = free). Row reductions are
// two intra-quad __shfl_xor steps instead of 4-step 16-lane chains.
// ---------------------------------------------------------------------------
__device__ __forceinline__ void ce_stage_load(const float4* __restrict__ scores4,
                                              int c, int tid, float4 st4[6])
{
    const float4* src = scores4 + (size_t)c * CHUNK_F4;
    #pragma unroll
    for (int k = 0; k < 5; ++k) st4[k] = src[k*256 + tid];
    if (tid < 16) st4[5] = src[1280 + tid];
}

__device__ __forceinline__ void ce_stage_write(float* bufp, int tid,
                                               const float4 st4[6])
{
    float4* dst = (float4*)bufp;
    #pragma unroll
    for (int k = 0; k < 5; ++k) dst[k*256 + tid] = st4[k];
    if (tid < 16) dst[1280 + tid] = st4[5];
}

__global__ __launch_bounds__(256) void ce_loc_kernel(
    const float* __restrict__ scores,   // [B,P,C]
    const float* __restrict__ locs,     // [B,P,4]
    const int*   __restrict__ tcls,     // [B,P]
    float*       __restrict__ conf_neg, // [B,P]
    float*       __restrict__ blk_pos,  // [NBLK_CE]
    float*       __restrict__ blk_loc)  // [NBLK_CE]
{
    const int tid  = threadIdx.x;
    const int lane = tid & 63;
    const int wv   = tid >> 6;
    const int s    = lane & 3;                  // sub-lane within row quad
    const int rl   = (lane >> 2) + wv * 16;     // row within chunk, 0..63

    __shared__ __attribute__((aligned(16))) float s_buf[2][ROWS_PER_CHUNK * C_];
    __shared__ float s_red[4][2];

    const int cnt   = (s == 0) ? 21 : 20;       // cols per sub-lane
    const int cbase = (s == 0) ? 0  : (1 + 20 * s);   // 0,21,41,61

    float p_acc = 0.f, l_acc = 0.f;
    const float4* scores4 = (const float4*)scores;

    float4 st4[6];

    // prologue: chunk blockIdx.x -> buf0
    int c0 = blockIdx.x;
    ce_stage_load(scores4, c0, tid, st4);
    ce_stage_write(s_buf[0], tid, st4);
    __syncthreads();

    int buf = 0;
    for (int c = c0; c < NCHUNKS; c += CE_GRID) {
        const int cn = c + CE_GRID;
        const bool have_next = (cn < NCHUNKS);
        if (have_next) ce_stage_load(scores4, cn, tid, st4);   // issue early

        // ---- compute chunk c from s_buf[buf] ----
        const float* rowp = &s_buf[buf][rl * C_ + cbase];
        float x[21];
        float mx = -INFINITY;
        #pragma unroll
        for (int k = 0; k < 21; ++k) {
            if (k < cnt) { x[k] = rowp[k]; mx = fmaxf(mx, x[k]); }
            else x[k] = -INFINITY;
        }
        mx = fmaxf(mx, __shfl_xor(mx, 1));
        mx = fmaxf(mx, __shfl_xor(mx, 2));

        const int row = c * ROWS_PER_CHUNK + rl;
        const int t = tcls[row];

        float e = 0.f, stv = 0.f;
        #pragma unroll
        for (int k = 0; k < 21; ++k) {
            e += __expf(x[k] - mx);                      // exp(-inf)=0 pad
            if ((cbase + k == t) && (k < cnt)) stv = x[k];
        }
        e   += __shfl_xor(e, 1);   e   += __shfl_xor(e, 2);
        stv += __shfl_xor(stv, 1); stv += __shfl_xor(stv, 2);

        if (s == 0) {
            float conf = mx + __logf(e) - stv;           // -log_softmax[t]
            if (t > 0) {
                conf_neg[row] = 0.f;
                p_acc += conf;
                // DIoU(box, box): inter_diag == 0; enclosing box == box
                float4 bx = ((const float4*)locs)[row];
                float w = bx.z - bx.x, h = bx.w - bx.y;
                float iw = fmaxf(w, 0.f), ih = fmaxf(h, 0.f);
                float inter = iw * ih;
                float area  = w * h;
                float iou   = inter / (area + area - inter + EPS_);
                float diou  = fminf(fmaxf(iou, -1.f), 1.f);
                l_acc += 1.f - diou;
            } else {
                conf_neg[row] = fmaxf(conf, 0.f);        // order-monotonic bits
            }
        }

        // write staged regs into the other buffer (vmcnt waited by data dep)
        if (have_next) ce_stage_write(s_buf[buf ^ 1], tid, st4);
        __syncthreads();
        buf ^= 1;
    }

    #pragma unroll
    for (int o = 32; o; o >>= 1) {
        p_acc += __shfl_xor(p_acc, o);
        l_acc += __shfl_xor(l_acc, o);
    }
    if (lane == 0) { s_red[wv][0] = p_acc; s_red[wv][1] = l_acc; }
    __syncthreads();
    if (tid == 0) {
        blk_pos[blockIdx.x] = s_red[0][0] + s_red[1][0] + s_red[2][0] + s_red[3][0];
        blk_loc[blockIdx.x] = s_red[0][1] + s_red[1][1] + s_red[2][1] + s_red[3][1];
    }
}

// ---------------------------------------------------------------------------
// Kernel 3: exact top-k sum (k = 3*n_pos[b]) per batch. 256-bin histogram
// radix select, 4 rounds, per-wave private histograms, tie-exact.
// (unchanged from verified version)
// ---------------------------------------------------------------------------
__global__ __launch_bounds__(1024) void topk_kernel(
    const float* __restrict__ conf_neg,
    const int*   __restrict__ n_pos,
    float*       __restrict__ hard)     // [B]
{
    const int b = blockIdx.x;
    const int tid = threadIdx.x;
    const int lane = tid & 63;
    const int wv = tid >> 6;

    __shared__ float s_v[P_];           // 34928 B
    __shared__ int   s_hist[16][256];   // 16384 B
    __shared__ int   s_cg[257];
    __shared__ int   s_sel;
    __shared__ int   s_t[16];
    __shared__ float s_f[16];

    for (int i = tid; i < P_; i += 1024) s_v[i] = conf_neg[(size_t)b*P_ + i];
    int k = 3 * n_pos[b];
    if (k <= 0) { if (tid == 0) hard[b] = 0.f; return; }  // block-uniform
    if (k > P_) k = P_;
    __syncthreads();

    const unsigned masks[4]  = {0u, 0xFF800000u, 0xFFFF8000u, 0xFFFFFF80u};
    const int      shifts[4] = {23, 15, 7, 0};

    unsigned prefix = 0u;
    int k_rem = k;

    for (int rd = 0; rd < 4; ++rd) {
        const unsigned hm = masks[rd];
        const int sh = shifts[rd];

        ((int*)s_hist)[tid] = 0;
        ((int*)s_hist)[tid + 1024] = 0;
        ((int*)s_hist)[tid + 2048] = 0;
        ((int*)s_hist)[tid + 3072] = 0;
        __syncthreads();

        for (int i = tid; i < P_; i += 1024) {
            unsigned u = __float_as_uint(s_v[i]);
            if ((u & hm) == prefix)
                atomicAdd(&s_hist[wv][(u >> sh) & 0xFF], 1);
        }
        __syncthreads();

        if (wv == 0) {
            int carry = 0;
            for (int cbin = 3; cbin >= 0; --cbin) {
                int bin = cbin * 64 + lane;
                int tot = 0;
                #pragma unroll
                for (int w = 0; w < 16; ++w) tot += s_hist[w][bin];
                #pragma unroll
                for (int o = 1; o < 64; o <<= 1) {
                    int v = __shfl_down(tot, o);
                    if (lane + o < 64) tot += v;
                }
                int cg = tot + carry;
                s_cg[bin] = cg;
                carry = __shfl(cg, 0);
            }
            if (lane == 0) s_cg[256] = 0;
        }
        __syncthreads();

        if (tid < 256) {
            if (s_cg[tid] >= k_rem && s_cg[tid + 1] < k_rem) s_sel = tid;
        }
        __syncthreads();

        const int bsel = s_sel;
        k_rem -= s_cg[bsel + 1];
        prefix |= (unsigned)bsel << sh;
        __syncthreads();
    }

    const float tval = __uint_as_float(prefix);   // exact k-th largest

    float sum = 0.f; int cgt = 0;
    for (int i = tid; i < P_; i += 1024) {
        float v = s_v[i];
        if (v > tval) { sum += v; cgt++; }
    }
    #pragma unroll
    for (int o = 32; o; o >>= 1) { sum += __shfl_xor(sum, o); cgt += __shfl_xor(cgt, o); }
    if (lane == 0) { s_f[wv] = sum; s_t[wv] = cgt; }
    __syncthreads();
    if (tid == 0) {
        float ssum = 0.f; int cc = 0;
        #pragma unroll
        for (int w = 0; w < 16; ++w) { ssum += s_f[w]; cc += s_t[w]; }
        hard[b] = ssum + (float)(k - cc) * tval;
    }
}

// ---------------------------------------------------------------------------
// Kernel 4: reduce partials + finalize scalar (NBLK_CE now 768)
// ---------------------------------------------------------------------------
__global__ __launch_bounds__(256) void final_kernel(
    const float* __restrict__ blk_pos,
    const float* __restrict__ blk_loc,
    const float* __restrict__ hard,
    const int*   __restrict__ n_pos,
    float*       __restrict__ out)
{
    const int tid = threadIdx.x;
    const int lane = tid & 63;
    const int wv = tid >> 6;
    __shared__ double sd[4][4];

    double p = 0.0, l = 0.0, h = 0.0, np = 0.0;
    for (int i = tid; i < NBLK_CE; i += 256) { p += blk_pos[i]; l += blk_loc[i]; }
    if (tid < B_) { h = hard[tid]; np = (double)n_pos[tid]; }

    #pragma unroll
    for (int o = 32; o; o >>= 1) {
        p += __shfl_xor(p, o); l += __shfl_xor(l, o);
        h += __shfl_xor(h, o); np += __shfl_xor(np, o);
    }
    if (lane == 0) { sd[wv][0] = p; sd[wv][1] = l; sd[wv][2] = h; sd[wv][3] = np; }
    __syncthreads();
    if (tid == 0) {
        double tp = 0, tl = 0, th = 0, tn = 0;
        #pragma unroll
        for (int w = 0; w < 4; ++w) { tp += sd[w][0]; tl += sd[w][1]; th += sd[w][2]; tn += sd[w][3]; }
        double conf_loss = (th + tp) / tn;
        double loc_loss  = tl / fmax(tn, 1.0);
        out[0] = (float)(conf_loss + 1.0 * loc_loss);
    }
}

extern "C" void kernel_launch(void* const* d_in, const int* in_sizes, int n_in,
                              void* d_out, int out_size, void* d_ws, size_t ws_size,
                              hipStream_t stream) {
    const float* predicted_locs   = (const float*)d_in[0];
    const float* predicted_scores = (const float*)d_in[1];
    const float* boxes            = (const float*)d_in[2];
    const int*   labels           = (const int*)d_in[3];
    const float* priors           = (const float*)d_in[4];
    float* out = (float*)d_out;

    char* ws = (char*)d_ws;
    size_t off = 0;
    int*    true_classes = (int*)(ws + off);   off += sizeof(int)   * (size_t)B_ * P_;
    float*  conf_neg     = (float*)(ws + off); off += sizeof(float) * (size_t)B_ * P_;
    int*    n_pos        = (int*)(ws + off);   off += sizeof(int)   * B_;
    float*  hard         = (float*)(ws + off); off += sizeof(float) * B_;
    float*  blk_pos      = (float*)(ws + off); off += sizeof(float) * NBLK_CE;
    float*  blk_loc      = (float*)(ws + off); off += sizeof(float) * NBLK_CE;

    assign_kernel<<<B_, 1024, 0, stream>>>(boxes, labels, priors,
                                           true_classes, n_pos);
    ce_loc_kernel<<<CE_GRID, 256, 0, stream>>>(predicted_scores, predicted_locs,
                                               true_classes, conf_neg,
                                               blk_pos, blk_loc);
    topk_kernel<<<B_, 1024, 0, stream>>>(conf_neg, n_pos, hard);
    final_kernel<<<1, 256, 0, stream>>>(blk_pos, blk_loc, hard, n_pos, out);
}

// Round 2
// 361.189 us; speedup vs baseline: 1.0499x; 1.0499x over previous
//
#include <hip/hip_runtime.h>
#include <math.h>

#define B_ 64
#define P_ 8732
#define M_ 16
#define C_ 81
#define THRESH 0.5f
#define EPS_ 1e-7f

#define ROWS_PER_CHUNK 64
#define NCHUNKS ((B_ * P_) / ROWS_PER_CHUNK)   // 558848/64 = 8732 exact
#define CHUNK_F4 (ROWS_PER_CHUNK * C_ / 4)     // 1296 float4 = 5*256 + 16

// ---------------------------------------------------------------------------
// Kernel 1: per-batch prior assignment. 1024 threads/block, one block/batch.
// Faithful to reference incl. j_idx filtered-index bug + last-write-wins.
// Also zeroes the topk completion counter (block 0) so the last-block
// finalize in topk starts clean every graph replay.
// ---------------------------------------------------------------------------
__global__ __launch_bounds__(1024) void assign_kernel(
    const float* __restrict__ boxes,    // [B,M,4] corner
    const int*   __restrict__ labels,   // [B,M]
    const float* __restrict__ priors,   // [P,4] cxcy
    int*         __restrict__ true_classes, // [B,P]
    int*         __restrict__ n_pos,    // [B]
    int*         __restrict__ done_ctr) // [1]
{
    const int b = blockIdx.x;
    const int tid = threadIdx.x;
    const int lane = tid & 63;
    const int wv = tid >> 6;            // 16 waves

    if (b == 0 && tid == 0) *done_ctr = 0;   // visible to topk at kernel boundary

    __shared__ float s_ovl[P_];
    __shared__ unsigned char s_obj[P_];
    __shared__ float s_bx[M_][4];
    __shared__ float s_barea[M_];
    __shared__ int   s_lab[M_];
    __shared__ float s_wv[M_][16];
    __shared__ int   s_wp[M_][16];
    __shared__ float s_ovl_obj[M_];
    __shared__ int   s_prior_obj[M_];
    __shared__ int   s_cnt[16];

    if (tid < M_*4) ((float*)s_bx)[tid] = boxes[b*M_*4 + tid];
    if (tid < M_)   s_lab[tid] = labels[b*M_ + tid];
    __syncthreads();
    if (tid < M_)
        s_barea[tid] = (s_bx[tid][2]-s_bx[tid][0])*(s_bx[tid][3]-s_bx[tid][1]);
    __syncthreads();

    float bestv[M_]; int bestp[M_];
    #pragma unroll
    for (int m = 0; m < M_; ++m) { bestv[m] = -1.0f; bestp[m] = 0x7fffffff; }

    for (int p = tid; p < P_; p += 1024) {
        float4 pc = ((const float4*)priors)[p];
        float px1 = pc.x - pc.z*0.5f, py1 = pc.y - pc.w*0.5f;
        float px2 = pc.x + pc.z*0.5f, py2 = pc.y + pc.w*0.5f;
        float parea = (px2-px1)*(py2-py1);
        float bv = -1.0f; int bm = 0;
        #pragma unroll
        for (int m = 0; m < M_; ++m) {
            float ix1 = fmaxf(s_bx[m][0], px1);
            float iy1 = fmaxf(s_bx[m][1], py1);
            float ix2 = fminf(s_bx[m][2], px2);
            float iy2 = fminf(s_bx[m][3], py2);
            float iw = fmaxf(ix2-ix1, 0.0f);
            float ih = fmaxf(iy2-iy1, 0.0f);
            float inter = iw*ih;
            float iou = inter / (s_barea[m] + parea - inter); // jaccard: no eps
            if (iou > bv) { bv = iou; bm = m; }               // first-max (m asc)
            if (iou > bestv[m]) { bestv[m] = iou; bestp[m] = p; } // first p wins
        }
        s_ovl[p] = bv;
        s_obj[p] = (unsigned char)bm;
    }

    #pragma unroll
    for (int m = 0; m < M_; ++m) {
        float v = bestv[m]; int p = bestp[m];
        #pragma unroll
        for (int o = 32; o; o >>= 1) {
            float v2 = __shfl_xor(v, o);
            int   p2 = __shfl_xor(p, o);
            if (v2 > v || (v2 == v && p2 < p)) { v = v2; p = p2; }
        }
        if (lane == 0) { s_wv[m][wv] = v; s_wp[m][wv] = p; }
    }
    __syncthreads();

    if (tid < M_) {
        float v = s_wv[tid][0]; int p = s_wp[tid][0];
        #pragma unroll
        for (int w = 1; w < 16; ++w) {
            float v2 = s_wv[tid][w]; int p2 = s_wp[tid][w];
            if (v2 > v || (v2 == v && p2 < p)) { v = v2; p = p2; }
        }
        s_ovl_obj[tid] = v; s_prior_obj[tid] = p;
    }
    __syncthreads();

    if (tid == 0) {
        int cnt = 0;
        for (int m = 0; m < M_; ++m) {
            if (s_ovl_obj[m] > 0.0f) {
                int p = s_prior_obj[m];
                s_ovl[p] = 1.0f;
                s_obj[p] = (unsigned char)cnt;  // filtered index (faithful)
                cnt++;
            }
        }
    }
    __syncthreads();

    int cpos = 0;
    for (int p = tid; p < P_; p += 1024) {
        int tc = 0;
        if (!(s_ovl[p] < THRESH)) tc = s_lab[s_obj[p]];
        true_classes[(size_t)b*P_ + p] = tc;
        cpos += (tc > 0);
    }
    #pragma unroll
    for (int o = 32; o; o >>= 1) cpos += __shfl_xor(cpos, o);
    if (lane == 0) s_cnt[wv] = cpos;
    __syncthreads();
    if (tid == 0) {
        int t = 0;
        #pragma unroll
        for (int w = 0; w < 16; ++w) t += s_cnt[w];
        n_pos[b] = t;
    }
}

// ---------------------------------------------------------------------------
// Kernel 2: CE over C=81 + positive-gated DIoU self-loss.
// ONE 64-row chunk per block (grid = 8732). Staging via
// __builtin_amdgcn_global_load_lds width=16: the chunk is exactly 1296
// aligned float4s and the layout is linear wave-uniform-base + lane*16 --
// fire-and-forget DMA, drained by the __syncthreads() barrier. No
// double-buffer serialization; 6+ blocks/CU keep HBM saturated.
// Compute: 4 lanes per row (cols 21/20/20/20), two intra-quad __shfl_xor
// reduction steps per quantity.
// ---------------------------------------------------------------------------
__global__ __launch_bounds__(256, 6) void ce_loc_kernel(
    const float* __restrict__ scores,   // [B,P,C]
    const float* __restrict__ locs,     // [B,P,4]
    const int*   __restrict__ tcls,     // [B,P]
    float*       __restrict__ conf_neg, // [B,P]
    float*       __restrict__ blk_pos,  // [NCHUNKS]
    float*       __restrict__ blk_loc)  // [NCHUNKS]
{
    const int c    = blockIdx.x;                // chunk index
    const int tid  = threadIdx.x;
    const int lane = tid & 63;
    const int wv   = tid >> 6;
    const int s    = lane & 3;                  // sub-lane within row quad
    const int rl   = (lane >> 2) + wv * 16;     // row within chunk, 0..63

    __shared__ __attribute__((aligned(16))) float s_buf[ROWS_PER_CHUNK * C_];
    __shared__ float s_red[4][2];

    const float4* src4 = (const float4*)scores + (size_t)c * CHUNK_F4;
    float4*       dst4 = (float4*)s_buf;

    // 5 full-block DMA steps: lds dest is wave-uniform base + lane*16 (linear)
    #pragma unroll
    for (int k = 0; k < 5; ++k) {
        __builtin_amdgcn_global_load_lds(
            (const __attribute__((address_space(1))) void*)(src4 + k*256 + tid),
            (__attribute__((address_space(3))) void*)(dst4 + k*256 + wv*64),
            16, 0, 0);
    }
    // 16-f4 tail via registers (wave 0 only)
    if (tid < 16) dst4[1280 + tid] = src4[1280 + tid];

    const int row = c * ROWS_PER_CHUNK + rl;
    const int t = tcls[row];                    // overlaps with staging
    __syncthreads();                            // drains vmcnt+lgkmcnt

    const int cnt   = (s == 0) ? 21 : 20;       // cols per sub-lane
    const int cbase = (s == 0) ? 0  : (1 + 20 * s);   // 0,21,41,61

    const float* rowp = &s_buf[rl * C_ + cbase];
    float x[21];
    float mx = -INFINITY;
    #pragma unroll
    for (int k = 0; k < 21; ++k) {
        if (k < cnt) { x[k] = rowp[k]; mx = fmaxf(mx, x[k]); }
        else x[k] = -INFINITY;
    }
    mx = fmaxf(mx, __shfl_xor(mx, 1));
    mx = fmaxf(mx, __shfl_xor(mx, 2));

    float e = 0.f, stv = 0.f;
    #pragma unroll
    for (int k = 0; k < 21; ++k) {
        e += __expf(x[k] - mx);                 // exp(-inf)=0 for pad
        if ((cbase + k == t) && (k < cnt)) stv = x[k];
    }
    e   += __shfl_xor(e, 1);   e   += __shfl_xor(e, 2);
    stv += __shfl_xor(stv, 1); stv += __shfl_xor(stv, 2);

    float p_acc = 0.f, l_acc = 0.f;
    if (s == 0) {
        float conf = mx + __logf(e) - stv;      // -log_softmax[t]
        if (t > 0) {
            conf_neg[row] = 0.f;
            p_acc = conf;
            // DIoU(box, box): inter_diag == 0; enclosing box == box
            float4 bx = ((const float4*)locs)[row];
            float w = bx.z - bx.x, h = bx.w - bx.y;
            float iw = fmaxf(w, 0.f), ih = fmaxf(h, 0.f);
            float inter = iw * ih;
            float area  = w * h;
            float iou   = inter / (area + area - inter + EPS_);
            float diou  = fminf(fmaxf(iou, -1.f), 1.f);
            l_acc = 1.f - diou;
        } else {
            conf_neg[row] = fmaxf(conf, 0.f);   // order-monotonic float bits
        }
    }

    #pragma unroll
    for (int o = 32; o; o >>= 1) {
        p_acc += __shfl_xor(p_acc, o);
        l_acc += __shfl_xor(l_acc, o);
    }
    if (lane == 0) { s_red[wv][0] = p_acc; s_red[wv][1] = l_acc; }
    __syncthreads();
    if (tid == 0) {
        blk_pos[c] = s_red[0][0] + s_red[1][0] + s_red[2][0] + s_red[3][0];
        blk_loc[c] = s_red[0][1] + s_red[1][1] + s_red[2][1] + s_red[3][1];
    }
}

// ---------------------------------------------------------------------------
// Kernel 3: exact top-k sum (k = 3*n_pos[b]) per batch (radix select,
// unchanged core) + LAST-BLOCK FINALIZE: the final scalar reduction is done
// by whichever block increments done_ctr to B-1 (device-scope atomics; no
// dispatch-order assumption). Deterministic summation order throughout.
// ---------------------------------------------------------------------------
__global__ __launch_bounds__(1024) void topk_kernel(
    const float* __restrict__ conf_neg, // [B,P]
    const int*   __restrict__ n_pos,    // [B]
    const float* __restrict__ blk_pos,  // [NCHUNKS]
    const float* __restrict__ blk_loc,  // [NCHUNKS]
    float*       __restrict__ hard,     // [B]
    int*         __restrict__ done_ctr, // [1]
    float*       __restrict__ out)      // [1]
{
    const int b = blockIdx.x;
    const int tid = threadIdx.x;
    const int lane = tid & 63;
    const int wv = tid >> 6;

    __shared__ float s_v[P_];           // 34928 B
    __shared__ int   s_hist[16][256];   // 16384 B
    __shared__ int   s_cg[257];
    __shared__ int   s_sel;
    __shared__ int   s_t[16];
    __shared__ float s_f[16];
    __shared__ int   s_last;
    __shared__ double sd[16][4];

    const float4* cn4 = (const float4*)(conf_neg + (size_t)b * P_);
    for (int i = tid; i < P_/4; i += 1024) ((float4*)s_v)[i] = cn4[i];

    int k = 3 * n_pos[b];
    if (k > P_) k = P_;

    float hsum = 0.f;                   // tid 0's value is the one that counts
    if (k > 0) {                        // block-uniform branch
        __syncthreads();

        const unsigned masks[4]  = {0u, 0xFF800000u, 0xFFFF8000u, 0xFFFFFF80u};
        const int      shifts[4] = {23, 15, 7, 0};

        unsigned prefix = 0u;
        int k_rem = k;

        for (int rd = 0; rd < 4; ++rd) {
            const unsigned hm = masks[rd];
            const int sh = shifts[rd];

            ((int*)s_hist)[tid] = 0;
            ((int*)s_hist)[tid + 1024] = 0;
            ((int*)s_hist)[tid + 2048] = 0;
            ((int*)s_hist)[tid + 3072] = 0;
            __syncthreads();

            for (int i = tid; i < P_; i += 1024) {
                unsigned u = __float_as_uint(s_v[i]);
                if ((u & hm) == prefix)
                    atomicAdd(&s_hist[wv][(u >> sh) & 0xFF], 1);
            }
            __syncthreads();

            if (wv == 0) {
                int carry = 0;
                for (int cbin = 3; cbin >= 0; --cbin) {
                    int bin = cbin * 64 + lane;
                    int tot = 0;
                    #pragma unroll
                    for (int w = 0; w < 16; ++w) tot += s_hist[w][bin];
                    #pragma unroll
                    for (int o = 1; o < 64; o <<= 1) {
                        int v = __shfl_down(tot, o);
                        if (lane + o < 64) tot += v;
                    }
                    int cg = tot + carry;
                    s_cg[bin] = cg;
                    carry = __shfl(cg, 0);
                }
                if (lane == 0) s_cg[256] = 0;
            }
            __syncthreads();

            if (tid < 256) {
                if (s_cg[tid] >= k_rem && s_cg[tid + 1] < k_rem) s_sel = tid;
            }
            __syncthreads();

            const int bsel = s_sel;
            k_rem -= s_cg[bsel + 1];
            prefix |= (unsigned)bsel << sh;
            __syncthreads();
        }

        const float tval = __uint_as_float(prefix);   // exact k-th largest

        float sum = 0.f; int cgt = 0;
        for (int i = tid; i < P_; i += 1024) {
            float v = s_v[i];
            if (v > tval) { sum += v; cgt++; }
        }
        #pragma unroll
        for (int o = 32; o; o >>= 1) { sum += __shfl_xor(sum, o); cgt += __shfl_xor(cgt, o); }
        if (lane == 0) { s_f[wv] = sum; s_t[wv] = cgt; }
        __syncthreads();
        if (tid == 0) {
            float ssum = 0.f; int cc = 0;
            #pragma unroll
            for (int w = 0; w < 16; ++w) { ssum += s_f[w]; cc += s_t[w]; }
            hsum = ssum + (float)(k - cc) * tval;
        }
    }

    // --- publish + last-block finalize ---
    if (tid == 0) {
        atomicExch(&hard[b], hsum);         // coherent-point store
        __threadfence();                    // release before counter bump
        s_last = (atomicAdd(done_ctr, 1) == B_ - 1) ? 1 : 0;
    }
    __syncthreads();

    if (s_last) {
        __threadfence();                    // acquire side
        double p = 0.0, l = 0.0;
        for (int i = tid; i < NCHUNKS; i += 1024) { p += blk_pos[i]; l += blk_loc[i]; }
        double h = 0.0, np = 0.0;
        if (tid < B_) {
            h  = (double)atomicAdd(&hard[tid], 0.0f);   // coherent-point read
            np = (double)n_pos[tid];
        }
        #pragma unroll
        for (int o = 32; o; o >>= 1) {
            p += __shfl_xor(p, o); l += __shfl_xor(l, o);
            h += __shfl_xor(h, o); np += __shfl_xor(np, o);
        }
        if (lane == 0) { sd[wv][0] = p; sd[wv][1] = l; sd[wv][2] = h; sd[wv][3] = np; }
        __syncthreads();
        if (tid == 0) {
            double tp = 0, tl = 0, th = 0, tn = 0;
            #pragma unroll
            for (int w = 0; w < 16; ++w) { tp += sd[w][0]; tl += sd[w][1]; th += sd[w][2]; tn += sd[w][3]; }
            double conf_loss = (th + tp) / tn;
            double loc_loss  = tl / fmax(tn, 1.0);
            out[0] = (float)(conf_loss + 1.0 * loc_loss);
        }
    }
}

extern "C" void kernel_launch(void* const* d_in, const int* in_sizes, int n_in,
                              void* d_out, int out_size, void* d_ws, size_t ws_size,
                              hipStream_t stream) {
    const float* predicted_locs   = (const float*)d_in[0];
    const float* predicted_scores = (const float*)d_in[1];
    const float* boxes            = (const float*)d_in[2];
    const int*   labels           = (const int*)d_in[3];
    const float* priors           = (const float*)d_in[4];
    float* out = (float*)d_out;

    char* ws = (char*)d_ws;
    size_t off = 0;
    int*    true_classes = (int*)(ws + off);   off += sizeof(int)   * (size_t)B_ * P_;
    float*  conf_neg     = (float*)(ws + off); off += sizeof(float) * (size_t)B_ * P_;
    float*  blk_pos      = (float*)(ws + off); off += sizeof(float) * NCHUNKS;
    float*  blk_loc      = (float*)(ws + off); off += sizeof(float) * NCHUNKS;
    float*  hard         = (float*)(ws + off); off += sizeof(float) * B_;
    int*    n_pos        = (int*)(ws + off);   off += sizeof(int)   * B_;
    int*    done_ctr     = (int*)(ws + off);   off += sizeof(int)   * 4;

    assign_kernel<<<B_, 1024, 0, stream>>>(boxes, labels, priors,
                                           true_classes, n_pos, done_ctr);
    ce_loc_kernel<<<NCHUNKS, 256, 0, stream>>>(predicted_scores, predicted_locs,
                                               true_classes, conf_neg,
                                               blk_pos, blk_loc);
    topk_kernel<<<B_, 1024, 0, stream>>>(conf_neg, n_pos, blk_pos, blk_loc,
                                         hard, done_ctr, out);
}